// Round 9
// baseline (137.012 us; speedup 1.0000x reference)
//
#include <hip/hip_runtime.h>
#include <math.h>

#define NT 1024
#define PW 68            // padded LDS row stride (68*4B = 16B-aligned rows)
#define RR 52            // staged X rows; r rows 0..49; v rows 1..48 (+ ring rows 0,49)
#define KB0 0x80000000u  // key(+0.0f) — border cells

// Order-preserving bijection f32 <-> u32 (monotone): max over keys == max over floats, exactly.
static __device__ __forceinline__ unsigned kenc(float f) {
    unsigned u = __float_as_uint(f);
    return ((int)u < 0) ? ~u : (u | 0x80000000u);
}
static __device__ __forceinline__ float kdec(unsigned k) {
    return __uint_as_float((k & 0x80000000u) ? (k ^ 0x80000000u) : ~k);
}

// Two launches: chunk<15,FIRST> then chunk<14,LAST>. 256 blocks, block = half image
// (32 core rows + 16-row internal halo; 48 v-rows/block).
// 16 waves: g2 = wid&1 -> channels 8*g2..8*g2+7 (weights wave-uniform -> SGPR);
// band = wid>>1 (0..7), 6 v-rows each; lane = column (0..63).
// Channel-max across the 2 groups via ds_max_u32 on encoded keys (exact, order-free).
// v buffers rotate 3-deep: compute reads p0, atomics into p1, p2 (dead) re-armed to 0.
template<int NIT, bool FIRST, bool LAST>
__global__ __launch_bounds__(NT)
void vin_chunk(const float* __restrict__ layout,
               const float* __restrict__ heatmap,
               const float* __restrict__ h_w,
               const float* __restrict__ h_b,
               const float* __restrict__ r_w,
               const float* __restrict__ q_w,
               const float* __restrict__ w,
               const float* __restrict__ fc_w,
               const int* __restrict__ S1,
               const int* __restrict__ S2,
               float* __restrict__ vg,
               float* __restrict__ out)
{
    __shared__ float    rh[28];
    __shared__ float    r_s[RR * PW];   // X0 bits, then r  (row M <-> image row vlo-1+M)
    __shared__ unsigned va[RR * PW];    // X1 bits, then v keys (v row L <-> image row vlo+L-1)
    __shared__ unsigned vb[RR * PW];    // X2 bits, then v keys
    __shared__ unsigned vc[RR * PW];    // v keys

    const int b2   = blockIdx.x;
    const int b    = b2 >> 1;
    const int half = b2 & 1;
    const int vlo  = half ? 16 : 0;
    const int tid  = threadIdx.x;

    // (a) zero staging buffers (borders must read as 0.0f during X/r phases)
    for (int i = tid; i < RR * PW; i += NT) { r_s[i] = 0.f; va[i] = 0u; vb[i] = 0u; }
    __syncthreads();

    // collapse 150-ch h-conv + 1x1 r-conv into 28 coeffs
    if (tid < 896) {
        const int coeff = tid >> 5, j = tid & 31;
        float s = 0.f;
        for (int cch = j; cch < 150; cch += 32)
            s += r_w[cch] * ((coeff < 27) ? h_w[cch * 27 + coeff] : h_b[cch]);
        s += __shfl_xor(s, 1, 32);  s += __shfl_xor(s, 2, 32);
        s += __shfl_xor(s, 4, 32);  s += __shfl_xor(s, 8, 32);
        s += __shfl_xor(s, 16, 32);
        if (j == 0) rh[coeff] = s;
    }
    // stage X rows M=0..51 <-> image rows vlo-2..vlo+49
    const float* X0 = layout  + (size_t)b * 2 * 4096;
    const float* X1 = X0 + 4096;
    const float* X2 = heatmap + (size_t)b * 4096;
    for (int i = tid; i < RR * 64; i += NT) {
        const int M = i >> 6, col = i & 63;
        const int ir = vlo - 2 + M;
        if (ir >= 0 && ir < 64) {
            const int s = ir * 64 + col, d = M * PW + 2 + col;
            r_s[d] = X0[s];
            va[d]  = __float_as_uint(X1[s]);
            vb[d]  = __float_as_uint(X2[s]);
        }
    }
    __syncthreads();  // X + rh ready

    // r rows 0..49 into registers
    float rv[4];
    int   rpx[4];
    #pragma unroll
    for (int k2 = 0; k2 < 4; ++k2) {
        const int i = tid + k2 * NT;
        rpx[k2] = -1;
        if (i < 50 * 64) {
            const int row = i >> 6, col = i & 63;
            float acc = rh[27];
            #pragma unroll
            for (int dy = 0; dy < 3; ++dy)
                #pragma unroll
                for (int dx = 0; dx < 3; ++dx) {
                    const int idx = (row + dy) * PW + 1 + col + dx;
                    acc = fmaf(rh[0 * 9 + dy * 3 + dx], r_s[idx], acc);
                    acc = fmaf(rh[1 * 9 + dy * 3 + dx], __uint_as_float(va[idx]), acc);
                    acc = fmaf(rh[2 * 9 + dy * 3 + dx], __uint_as_float(vb[idx]), acc);
                }
            const int ir = vlo - 1 + row;
            rv[k2]  = (ir >= 0 && ir < 64) ? acc : 0.f;
            rpx[k2] = row * PW + 2 + col;
        }
    }
    __syncthreads();  // X consumed

    // write r; arm key buffers (rows 0..49): borders = key(0), interior = 0 (atomic id)
    // or staged-v keys for va when !FIRST. No races: each cell written by one thread.
    for (int i = tid; i < 50 * PW; i += NT) {
        const int row = i / PW, cc = i - row * PW;
        const bool border = (row == 0) | (row == 49) | (cc < 2) | (cc > 65);
        unsigned vav;
        if (FIRST) vav = border ? KB0 : 0u;
        else       vav = border ? KB0 : kenc(vg[b * 4096 + (vlo + row - 1) * 64 + (cc - 2)]);
        va[i] = vav;
        vb[i] = border ? KB0 : 0u;
        vc[i] = border ? KB0 : 0u;
    }
    #pragma unroll
    for (int k2 = 0; k2 < 4; ++k2) if (rpx[k2] >= 0) r_s[rpx[k2]] = rv[k2];
    __syncthreads();  // r + armed key buffers ready

    // per-lane geometry
    const int wid  = tid >> 6, lane = tid & 63;
    const int g2   = wid & 1;        // channel group: channels 8*g2..8*g2+7
    const int band = wid >> 1;       // 0..7
    const int rb0  = band * 6;       // window-top row for j=0 (v rows rb0+1..rb0+6)
    const int c    = lane;           // column 0..63
    const int gu   = __builtin_amdgcn_readfirstlane(g2);

    // rq[o*6+j] = conv3x3(r, q_w[8*gu+o]); weights wave-uniform -> SGPR
    float rq[48];
    {
        float wqs[72];
        #pragma unroll
        for (int t = 0; t < 72; ++t)
            wqs[t] = __int_as_float(__builtin_amdgcn_readfirstlane(
                         __float_as_int(q_w[gu * 72 + t])));
        float a0[3], a1[3], a2[3];
        #pragma unroll
        for (int d = 0; d < 3; ++d) {
            a0[d] = r_s[rb0 * PW + 1 + c + d];
            a1[d] = r_s[(rb0 + 1) * PW + 1 + c + d];
        }
        #pragma unroll
        for (int j = 0; j < 6; ++j) {
            #pragma unroll
            for (int d = 0; d < 3; ++d) a2[d] = r_s[(rb0 + j + 2) * PW + 1 + c + d];
            float m = 0.f;
            #pragma unroll
            for (int o = 0; o < 8; ++o) {
                float q = 0.f;
                q = fmaf(wqs[o*9+0], a0[0], q); q = fmaf(wqs[o*9+1], a0[1], q); q = fmaf(wqs[o*9+2], a0[2], q);
                q = fmaf(wqs[o*9+3], a1[0], q); q = fmaf(wqs[o*9+4], a1[1], q); q = fmaf(wqs[o*9+5], a1[2], q);
                q = fmaf(wqs[o*9+6], a2[0], q); q = fmaf(wqs[o*9+7], a2[1], q); q = fmaf(wqs[o*9+8], a2[2], q);
                rq[o * 6 + j] = q;
                m = (o == 0) ? q : fmaxf(m, q);
            }
            if (FIRST) atomicMax(&va[(rb0 + 1 + j) * PW + 2 + c], kenc(m));
            #pragma unroll
            for (int d = 0; d < 3; ++d) { a0[d] = a1[d]; a1[d] = a2[d]; }
        }
    }

    float wvs[72];
    #pragma unroll
    for (int t = 0; t < 72; ++t)
        wvs[t] = __int_as_float(__builtin_amdgcn_readfirstlane(
                     __float_as_int(w[gu * 72 + t])));
    __syncthreads();  // v0 ready (FIRST) / staged v ready

    // NIT sweeps: read p0, atomic-max into p1, re-arm p2; one barrier each
    unsigned* p0 = va;
    unsigned* p1 = vb;
    unsigned* p2 = vc;
    uint2 z2; z2.x = 0u; z2.y = 0u;
    #pragma unroll 1
    for (int it = 0; it < NIT; ++it) {
        { const int t = tid;        const int row = (t >> 5) + 1, pr = t & 31;
          *reinterpret_cast<uint2*>(&p2[row * PW + 2 + 2 * pr]) = z2; }
        if (tid < 512) {
          const int t = tid + 1024; const int row = (t >> 5) + 1, pr = t & 31;
          *reinterpret_cast<uint2*>(&p2[row * PW + 2 + 2 * pr]) = z2; }

        float a0[3], a1[3], a2[3];
        #pragma unroll
        for (int d = 0; d < 3; ++d) {
            a0[d] = kdec(p0[rb0 * PW + 1 + c + d]);
            a1[d] = kdec(p0[(rb0 + 1) * PW + 1 + c + d]);
        }
        #pragma unroll
        for (int j = 0; j < 6; ++j) {
            #pragma unroll
            for (int d = 0; d < 3; ++d) a2[d] = kdec(p0[(rb0 + j + 2) * PW + 1 + c + d]);
            float m = 0.f;
            #pragma unroll
            for (int o = 0; o < 8; ++o) {
                float q = rq[o * 6 + j];
                q = fmaf(wvs[o*9+0], a0[0], q); q = fmaf(wvs[o*9+1], a0[1], q); q = fmaf(wvs[o*9+2], a0[2], q);
                q = fmaf(wvs[o*9+3], a1[0], q); q = fmaf(wvs[o*9+4], a1[1], q); q = fmaf(wvs[o*9+5], a1[2], q);
                q = fmaf(wvs[o*9+6], a2[0], q); q = fmaf(wvs[o*9+7], a2[1], q); q = fmaf(wvs[o*9+8], a2[2], q);
                m = (o == 0) ? q : fmaxf(m, q);
            }
            atomicMax(&p1[(rb0 + 1 + j) * PW + 2 + c], kenc(m));
            #pragma unroll
            for (int d = 0; d < 3; ++d) { a0[d] = a1[d]; a1[d] = a2[d]; }
        }
        __syncthreads();
        unsigned* tp = p0; p0 = p1; p1 = p2; p2 = tp;
    }

    // writeback core rows (image half*32 .. half*32+31; L = ir - vlo + 1)
    if (!LAST) {
        for (int i = tid; i < 32 * 64; i += NT) {
            const int ir = half * 32 + (i >> 6), col = i & 63;
            vg[b * 4096 + ir * 64 + col] = kdec(p0[(ir - vlo + 1) * PW + 2 + col]);
        }
    } else {
        float* out_v = out + 1024 + (size_t)b * 4096;
        for (int i = tid; i < 32 * 64; i += NT) {
            const int ir = half * 32 + (i >> 6), col = i & 63;
            out_v[ir * 64 + col] = kdec(p0[(ir - vlo + 1) * PW + 2 + col]);
        }
    }
    if (FIRST) {
        float* out_r = out + 1024 + (size_t)128 * 4096 + (size_t)b * 4096;
        float* out_h = out + 1024 + (size_t)256 * 4096 + (size_t)b * 4096;
        for (int i = tid; i < 32 * 64; i += NT) {
            const int ir = half * 32 + (i >> 6), col = i & 63;
            out_r[ir * 64 + col] = r_s[(ir - vlo + 1) * PW + 2 + col];
            out_h[ir * 64 + col] = X2[ir * 64 + col];
        }
    }

    if (LAST) {
        const int s1 = S1[b], s2 = S2[b];
        if ((s1 >> 5) == half && tid == 0) {
            float q16[16];
            #pragma unroll
            for (int o = 0; o < 16; ++o) {
                float acc = 0.f;
                #pragma unroll
                for (int dy = 0; dy < 3; ++dy)
                    #pragma unroll
                    for (int dx = 0; dx < 3; ++dx) {
                        const int li = (s1 + dy - vlo) * PW + 1 + s2 + dx;
                        acc = fmaf(q_w[o * 9 + dy * 3 + dx], r_s[li], acc);
                        acc = fmaf(w[o * 9 + dy * 3 + dx],  kdec(p0[li]), acc);
                    }
                q16[o] = acc;
            }
            float lg[4];
            #pragma unroll
            for (int j = 0; j < 4; ++j) {
                float a = 0.f;
                #pragma unroll
                for (int o = 0; o < 16; ++o) a = fmaf(fc_w[j * 16 + o], q16[o], a);
                lg[j] = a;
            }
            const float m  = fmaxf(fmaxf(lg[0], lg[1]), fmaxf(lg[2], lg[3]));
            const float e0 = expf(lg[0] - m), e1 = expf(lg[1] - m);
            const float e2 = expf(lg[2] - m), e3 = expf(lg[3] - m);
            const float s  = e0 + e1 + e2 + e3;
            out[b * 4 + 0] = lg[0]; out[b * 4 + 1] = lg[1];
            out[b * 4 + 2] = lg[2]; out[b * 4 + 3] = lg[3];
            out[512 + b * 4 + 0] = e0 / s; out[512 + b * 4 + 1] = e1 / s;
            out[512 + b * 4 + 2] = e2 / s; out[512 + b * 4 + 3] = e3 / s;
        }
    }
}

extern "C" void kernel_launch(void* const* d_in, const int* in_sizes, int n_in,
                              void* d_out, int out_size, void* d_ws, size_t ws_size,
                              hipStream_t stream) {
    const float* layout  = (const float*)d_in[0];
    const float* heatmap = (const float*)d_in[1];
    const float* h_w     = (const float*)d_in[2];
    const float* h_b     = (const float*)d_in[3];
    const float* r_w     = (const float*)d_in[4];
    const float* q_w     = (const float*)d_in[5];
    const float* w       = (const float*)d_in[6];
    const float* fc_w    = (const float*)d_in[7];
    const int*   S1      = (const int*)d_in[8];
    const int*   S2      = (const int*)d_in[9];
    float* out = (float*)d_out;
    float* vg  = (float*)d_ws;   // 128*4096 f32 = 2 MB

    hipLaunchKernelGGL((vin_chunk<15, true,  false>), dim3(256), dim3(NT), 0, stream,
                       layout, heatmap, h_w, h_b, r_w, q_w, w, fc_w, S1, S2, vg, out);
    hipLaunchKernelGGL((vin_chunk<14, false, true>),  dim3(256), dim3(NT), 0, stream,
                       layout, heatmap, h_w, h_b, r_w, q_w, w, fc_w, S1, S2, vg, out);
}

// Round 10
// 116.536 us; speedup vs baseline: 1.1757x; 1.1757x over previous
//
#include <hip/hip_runtime.h>
#include <math.h>

#define NT 1024
#define PW 66      // padded LDS row stride
#define RR 52      // LDS buffer rows (52 X rows / 50 r rows / 48 v rows + ring)

// Two launches: chunk<15,FIRST> then chunk<14,LAST>. 256 blocks (1 per CU),
// block = half image (32 core rows + 16-row internal halo).
// Wave = 16 pixel-cols x 4 channel-groups: lane: g = lane>>4 (channels 4g..4g+3),
// p = lane&15, col c=(wid&3)*16+p, rows band*12..band*12+11 (band = wid>>2).
//
// lds_force[10240] (40KB dead pad): pushes LDS to ~82KB so only ONE workgroup
// fits per CU -> occupancy cap 16 waves/CU = 4/SIMD -> register allocator gets
// the 128-VGPR budget instead of the 64-VGPR budget it targeted for the
// (unreachable, grid==#CUs) 2-WG/CU case. Rounds 2-9 were stuck at
// VGPR_Count=64 with ~110 live values -> AGPR shuttling ~1.8x VALU emission;
// __launch_bounds__ min-blocks and amdgpu_waves_per_eu both failed to move it.
template<int NIT, bool FIRST, bool LAST>
__global__ __launch_bounds__(NT)
void vin_chunk(const float* __restrict__ layout,
               const float* __restrict__ heatmap,
               const float* __restrict__ h_w,
               const float* __restrict__ h_b,
               const float* __restrict__ r_w,
               const float* __restrict__ q_w,
               const float* __restrict__ w,
               const float* __restrict__ fc_w,
               const int* __restrict__ S1,
               const int* __restrict__ S2,
               float* __restrict__ vg,
               float* __restrict__ out)
{
    __shared__ float rh[28];
    __shared__ float r_s[RR * PW];   // X0, then r   (r_s row M <-> image row vlo-1+M)
    __shared__ float va[RR * PW];    // X1, then v ping (v row L <-> image row vlo+L-1)
    __shared__ float vb[RR * PW];    // X2, then v pong
    __shared__ float lds_force[10240];  // dead 40KB pad -> 1 WG/CU -> 128-VGPR budget

    const int b2   = blockIdx.x;
    const int b    = b2 >> 1;
    const int half = b2 & 1;
    const int vlo  = half ? 16 : 0;
    const int tid  = threadIdx.x;

    // keep lds_force allocated: block-uniform, data-dependent, never taken
    if (h_b[0] == 1234.56789f) { lds_force[tid] = h_b[1]; }

    // B0: zero everything (borders must be 0)
    for (int i = tid; i < RR * PW; i += NT) { r_s[i] = 0.f; va[i] = 0.f; vb[i] = 0.f; }
    __syncthreads();

    // collapse 150-ch h-conv + 1x1 r-conv into 28 coeffs (32 threads per coeff)
    if (tid < 896) {
        const int coeff = tid >> 5, j = tid & 31;
        float s = 0.f;
        for (int c = j; c < 150; c += 32)
            s += r_w[c] * ((coeff < 27) ? h_w[c * 27 + coeff] : h_b[c]);
        s += __shfl_xor(s, 1, 32);  s += __shfl_xor(s, 2, 32);
        s += __shfl_xor(s, 4, 32);  s += __shfl_xor(s, 8, 32);
        s += __shfl_xor(s, 16, 32);
        if (j == 0) rh[coeff] = s;
    }
    // stage X rows M=0..51 <-> image rows vlo-2..vlo+49 (zero OOB kept from memset)
    const float* X0 = layout  + (size_t)b * 2 * 4096;
    const float* X1 = X0 + 4096;
    const float* X2 = heatmap + (size_t)b * 4096;
    for (int i = tid; i < RR * 64; i += NT) {
        const int M = i >> 6, col = i & 63;
        const int ir = vlo - 2 + M;
        if (ir >= 0 && ir < 64) {
            const int s = ir * 64 + col, d = M * PW + col + 1;
            r_s[d] = X0[s]; va[d] = X1[s]; vb[d] = X2[s];
        }
    }
    __syncthreads();  // B1: X + rh ready

    // r (rows 0..49, cols 0..63) into registers; window top X-row == dest r-row
    float rv[4];
    int   rpx[4];
    #pragma unroll
    for (int k2 = 0; k2 < 4; ++k2) {
        const int i = tid + k2 * NT;
        rpx[k2] = -1;
        if (i < 50 * 64) {
            const int row = i >> 6, col = i & 63;
            float acc = rh[27];
            #pragma unroll
            for (int dy = 0; dy < 3; ++dy)
                #pragma unroll
                for (int dx = 0; dx < 3; ++dx) {
                    const int idx = (row + dy) * PW + col + dx;
                    acc = fmaf(rh[0 * 9 + dy * 3 + dx], r_s[idx], acc);
                    acc = fmaf(rh[1 * 9 + dy * 3 + dx], va[idx],  acc);
                    acc = fmaf(rh[2 * 9 + dy * 3 + dx], vb[idx],  acc);
                }
            const int ir = vlo - 1 + row;
            rv[k2]  = (ir >= 0 && ir < 64) ? acc : 0.f;  // true zero padding
            rpx[k2] = row * PW + col + 1;
        }
    }
    __syncthreads();  // B2: X consumed

    // overwrite: r -> r_s, re-zero v buffers
    for (int i = tid; i < RR * PW; i += NT) { va[i] = 0.f; vb[i] = 0.f; }
    #pragma unroll
    for (int k2 = 0; k2 < 4; ++k2) if (rpx[k2] >= 0) r_s[rpx[k2]] = rv[k2];
    __syncthreads();  // B3: r ready, v buffers zero

    // per-lane geometry
    const int wid  = tid >> 6, lane = tid & 63;
    const int g    = lane >> 4;      // channel group: channels 4g..4g+3
    const int p    = lane & 15;      // pixel slot 0..15
    const int c    = (wid & 3) * 16 + p;
    const int band = wid >> 2;
    const int rb0  = band * 12;      // conv-window top LDS row for j=0

    // stage v (non-FIRST) rows 1..48 <- vg image rows vlo..vlo+47
    if (!FIRST) {
        for (int i = tid; i < 48 * 64; i += NT) {
            const int L = (i >> 6) + 1, col = i & 63;
            va[L * PW + col + 1] = vg[b * 4096 + (vlo + L - 1) * 64 + col];
        }
    }

    // rq[cc*12+j] = conv3x3(r, q_w[4g+cc]) at (row 1+rb0+j, col c); v0 if FIRST
    float wq[36];
    #pragma unroll
    for (int t = 0; t < 36; ++t) wq[t] = q_w[g * 36 + t];

    float rq[48];
    {
        const float* rw = r_s + rb0 * PW + c;
        float a0[3], a1[3], a2[3];
        #pragma unroll
        for (int d = 0; d < 3; ++d) { a0[d] = rw[d]; a1[d] = rw[PW + d]; }
        #pragma unroll
        for (int j = 0; j < 12; ++j) {
            #pragma unroll
            for (int d = 0; d < 3; ++d) a2[d] = rw[(j + 2) * PW + d];
            #pragma unroll
            for (int cc = 0; cc < 4; ++cc) {
                float a = 0.f;
                #pragma unroll
                for (int d = 0; d < 3; ++d) {
                    a = fmaf(wq[cc * 9 + d],     a0[d], a);
                    a = fmaf(wq[cc * 9 + 3 + d], a1[d], a);
                    a = fmaf(wq[cc * 9 + 6 + d], a2[d], a);
                }
                rq[cc * 12 + j] = a;
            }
            if (FIRST) {
                float m = fmaxf(fmaxf(rq[0 * 12 + j], rq[1 * 12 + j]),
                                fmaxf(rq[2 * 12 + j], rq[3 * 12 + j]));
                m = fmaxf(m, __shfl_xor(m, 16));
                m = fmaxf(m, __shfl_xor(m, 32));
                if (g == 0) va[(1 + rb0 + j) * PW + c + 1] = m;
            }
            #pragma unroll
            for (int d = 0; d < 3; ++d) { a0[d] = a1[d]; a1[d] = a2[d]; }
        }
    }

    float wv[36];
    #pragma unroll
    for (int t = 0; t < 36; ++t) wv[t] = w[g * 36 + t];
    __syncthreads();  // B4: v0 / staged v ready

    // NIT sweeps
    float* vcur = va;
    float* vnxt = vb;
    #pragma unroll 1
    for (int it = 0; it < NIT; ++it) {
        const float* vw = vcur + rb0 * PW + c;
        float a0[3], a1[3], a2[3];
        #pragma unroll
        for (int d = 0; d < 3; ++d) { a0[d] = vw[d]; a1[d] = vw[PW + d]; }
        #pragma unroll
        for (int j = 0; j < 12; ++j) {
            #pragma unroll
            for (int d = 0; d < 3; ++d) a2[d] = vw[(j + 2) * PW + d];
            float q0 = rq[0 * 12 + j], q1 = rq[1 * 12 + j];
            float q2 = rq[2 * 12 + j], q3 = rq[3 * 12 + j];
            #pragma unroll
            for (int d = 0; d < 3; ++d) {
                q0 = fmaf(wv[0 + d],  a0[d], q0); q0 = fmaf(wv[3 + d],  a1[d], q0); q0 = fmaf(wv[6 + d],  a2[d], q0);
                q1 = fmaf(wv[9 + d],  a0[d], q1); q1 = fmaf(wv[12 + d], a1[d], q1); q1 = fmaf(wv[15 + d], a2[d], q1);
                q2 = fmaf(wv[18 + d], a0[d], q2); q2 = fmaf(wv[21 + d], a1[d], q2); q2 = fmaf(wv[24 + d], a2[d], q2);
                q3 = fmaf(wv[27 + d], a0[d], q3); q3 = fmaf(wv[30 + d], a1[d], q3); q3 = fmaf(wv[33 + d], a2[d], q3);
            }
            float m = fmaxf(fmaxf(q0, q1), fmaxf(q2, q3));
            m = fmaxf(m, __shfl_xor(m, 16));
            m = fmaxf(m, __shfl_xor(m, 32));
            if (g == 0) vnxt[(1 + rb0 + j) * PW + c + 1] = m;
            #pragma unroll
            for (int d = 0; d < 3; ++d) { a0[d] = a1[d]; a1[d] = a2[d]; }
        }
        __syncthreads();
        float* t = vcur; vcur = vnxt; vnxt = t;
    }

    // writeback core rows (image half*32 .. half*32+31; L = ir - vlo + 1)
    if (!LAST) {
        for (int i = tid; i < 32 * 64; i += NT) {
            const int ir = half * 32 + (i >> 6), col = i & 63;
            vg[b * 4096 + ir * 64 + col] = vcur[(ir - vlo + 1) * PW + col + 1];
        }
    } else {
        float* out_v = out + 1024 + (size_t)b * 4096;
        for (int i = tid; i < 32 * 64; i += NT) {
            const int ir = half * 32 + (i >> 6), col = i & 63;
            out_v[ir * 64 + col] = vcur[(ir - vlo + 1) * PW + col + 1];
        }
    }
    if (FIRST) {
        float* out_r = out + 1024 + (size_t)128 * 4096 + (size_t)b * 4096;
        float* out_h = out + 1024 + (size_t)256 * 4096 + (size_t)b * 4096;
        for (int i = tid; i < 32 * 64; i += NT) {
            const int ir = half * 32 + (i >> 6), col = i & 63;
            out_r[ir * 64 + col] = r_s[(ir - vlo + 1) * PW + col + 1];
            out_h[ir * 64 + col] = X2[ir * 64 + col];
        }
    }

    if (LAST) {
        const int s1 = S1[b], s2 = S2[b];
        if ((s1 >> 5) == half && tid == 0) {
            float q16[16];
            #pragma unroll
            for (int o = 0; o < 16; ++o) {
                float acc = 0.f;
                #pragma unroll
                for (int dy = 0; dy < 3; ++dy)
                    #pragma unroll
                    for (int dx = 0; dx < 3; ++dx) {
                        const int li = (s1 + dy - vlo) * PW + s2 + dx;
                        acc = fmaf(q_w[o * 9 + dy * 3 + dx], r_s[li], acc);
                        acc = fmaf(w[o * 9 + dy * 3 + dx],  vcur[li], acc);
                    }
                q16[o] = acc;
            }
            float lg[4];
            #pragma unroll
            for (int j = 0; j < 4; ++j) {
                float a = 0.f;
                #pragma unroll
                for (int o = 0; o < 16; ++o) a = fmaf(fc_w[j * 16 + o], q16[o], a);
                lg[j] = a;
            }
            const float m  = fmaxf(fmaxf(lg[0], lg[1]), fmaxf(lg[2], lg[3]));
            const float e0 = expf(lg[0] - m), e1 = expf(lg[1] - m);
            const float e2 = expf(lg[2] - m), e3 = expf(lg[3] - m);
            const float s  = e0 + e1 + e2 + e3;
            out[b * 4 + 0] = lg[0]; out[b * 4 + 1] = lg[1];
            out[b * 4 + 2] = lg[2]; out[b * 4 + 3] = lg[3];
            out[512 + b * 4 + 0] = e0 / s; out[512 + b * 4 + 1] = e1 / s;
            out[512 + b * 4 + 2] = e2 / s; out[512 + b * 4 + 3] = e3 / s;
        }
    }
}

extern "C" void kernel_launch(void* const* d_in, const int* in_sizes, int n_in,
                              void* d_out, int out_size, void* d_ws, size_t ws_size,
                              hipStream_t stream) {
    const float* layout  = (const float*)d_in[0];
    const float* heatmap = (const float*)d_in[1];
    const float* h_w     = (const float*)d_in[2];
    const float* h_b     = (const float*)d_in[3];
    const float* r_w     = (const float*)d_in[4];
    const float* q_w     = (const float*)d_in[5];
    const float* w       = (const float*)d_in[6];
    const float* fc_w    = (const float*)d_in[7];
    const int*   S1      = (const int*)d_in[8];
    const int*   S2      = (const int*)d_in[9];
    float* out = (float*)d_out;
    float* vg  = (float*)d_ws;   // 128*4096 f32 = 2 MB

    hipLaunchKernelGGL((vin_chunk<15, true,  false>), dim3(256), dim3(NT), 0, stream,
                       layout, heatmap, h_w, h_b, r_w, q_w, w, fc_w, S1, S2, vg, out);
    hipLaunchKernelGGL((vin_chunk<14, false, true>),  dim3(256), dim3(NT), 0, stream,
                       layout, heatmap, h_w, h_b, r_w, q_w, w, fc_w, S1, S2, vg, out);
}